// Round 1
// baseline (13319.815 us; speedup 1.0000x reference)
//
#include <hip/hip_runtime.h>
#include <cstddef>

#define B_ 64
#define T_ 32
#define S_ 128
#define IN_ 1024
#define H_ 1024

__device__ __forceinline__ float sigmoidf_(float x) { return 1.0f / (1.0f + expf(-x)); }

// C[M,N] = A[M,K] @ B[N,K]^T  (+ bias[n]) (+ Cadd[m,n]) (act: 0=none, 1=tanh)
// Tile 64x64, 256 threads, 4x4 per thread, BK=16.
__global__ __launch_bounds__(256) void gemm_abt(
    const float* __restrict__ A, long lda,
    const float* __restrict__ Bm, long ldb,
    float* __restrict__ C, long ldc,
    int K,
    const float* __restrict__ bias,
    const float* __restrict__ Cadd, long ldadd,
    int act)
{
    __shared__ float As[16][68];
    __shared__ float Bs[16][68];
    const int tid = threadIdx.x;
    const int m0 = blockIdx.y * 64;
    const int n0 = blockIdx.x * 64;
    const int lk = tid & 15;   // k within tile (load)
    const int lr = tid >> 4;   // row group (load)
    const int tx = tid & 15;   // n micro-tile
    const int ty = tid >> 4;   // m micro-tile

    float acc[4][4] = {};

    const float* Ab = A + (size_t)m0 * lda + lk;
    const float* Bb = Bm + (size_t)n0 * ldb + lk;

    for (int k0 = 0; k0 < K; k0 += 16) {
#pragma unroll
        for (int i = 0; i < 4; ++i) {
            As[lk][lr + 16 * i] = Ab[(size_t)(lr + 16 * i) * lda + k0];
            Bs[lk][lr + 16 * i] = Bb[(size_t)(lr + 16 * i) * ldb + k0];
        }
        __syncthreads();
#pragma unroll
        for (int kk = 0; kk < 16; ++kk) {
            const float4 av = *reinterpret_cast<const float4*>(&As[kk][ty * 4]);
            const float4 bv = *reinterpret_cast<const float4*>(&Bs[kk][tx * 4]);
            const float a[4] = {av.x, av.y, av.z, av.w};
            const float b[4] = {bv.x, bv.y, bv.z, bv.w};
#pragma unroll
            for (int i = 0; i < 4; ++i)
#pragma unroll
                for (int j = 0; j < 4; ++j)
                    acc[i][j] += a[i] * b[j];
        }
        __syncthreads();
    }

#pragma unroll
    for (int i = 0; i < 4; ++i) {
        const int m = m0 + ty * 4 + i;
#pragma unroll
        for (int j = 0; j < 4; ++j) {
            const int n = n0 + tx * 4 + j;
            float v = acc[i][j];
            if (bias) v += bias[n];
            if (Cadd) v += Cadd[(size_t)m * ldadd + n];
            if (act == 1) v = tanhf(v);
            C[(size_t)m * ldc + n] = v;
        }
    }
}

__global__ __launch_bounds__(256) void lstm_cell(
    const float* __restrict__ gates, float* __restrict__ c_buf, float* __restrict__ hy)
{
    const int idx = blockIdx.x * 256 + threadIdx.x;  // < B*H
    const int b = idx >> 10;
    const int j = idx & 1023;
    const float* g = gates + (size_t)b * 4 * H_;
    const float ig = sigmoidf_(g[j]);
    const float fg = sigmoidf_(g[H_ + j]);
    const float gg = tanhf(g[2 * H_ + j]);
    const float og = sigmoidf_(g[3 * H_ + j]);
    const float c = fg * c_buf[idx] + ig * gg;
    c_buf[idx] = c;
    hy[idx] = og * tanhf(c);
}

// One block per batch element. Computes scores = dense_ctx[b] @ inp[b] - neg,
// softmax over S, then wctx[b] = a @ dense_ctx[b]. inp lives at A_cat[:,1024:2048];
// wctx written to A_cat[:,0:1024].
__global__ __launch_bounds__(256) void attn_kernel(
    const float* __restrict__ dense_ctx, float* __restrict__ A_cat,
    const float* __restrict__ mask)
{
    const int b = blockIdx.x;
    const int tid = threadIdx.x;
    const int lane = tid & 63;
    const int wid = tid >> 6;

    __shared__ float sc[S_];

    const float* dc = dense_ctx + (size_t)b * S_ * IN_;
    const float* inp = A_cat + (size_t)b * 2 * IN_ + IN_;

    // scores
    for (int s = wid; s < S_; s += 4) {
        const float* row = dc + (size_t)s * IN_;
        float sum = 0.0f;
        for (int k = lane; k < IN_; k += 64) sum += row[k] * inp[k];
#pragma unroll
        for (int off = 32; off > 0; off >>= 1) sum += __shfl_xor(sum, off);
        if (lane == 0)
            sc[s] = sum - (1.0f - mask[(size_t)b * S_ + s]) * 100000.0f;
    }
    __syncthreads();

    // softmax (wave 0 handles all 128 scores)
    if (tid < 64) {
        float v0 = sc[tid], v1 = sc[tid + 64];
        float mx = fmaxf(v0, v1);
#pragma unroll
        for (int off = 32; off > 0; off >>= 1) mx = fmaxf(mx, __shfl_xor(mx, off));
        float e0 = expf(v0 - mx), e1 = expf(v1 - mx);
        float ssum = e0 + e1;
#pragma unroll
        for (int off = 32; off > 0; off >>= 1) ssum += __shfl_xor(ssum, off);
        const float inv = 1.0f / ssum;
        sc[tid] = e0 * inv;
        sc[tid + 64] = e1 * inv;
    }
    __syncthreads();

    // wctx
    float acc[4] = {0.0f, 0.0f, 0.0f, 0.0f};
    for (int s = 0; s < S_; ++s) {
        const float a = sc[s];
        const float* row = dc + (size_t)s * IN_;
#pragma unroll
        for (int q = 0; q < 4; ++q) acc[q] += a * row[tid + q * 256];
    }
#pragma unroll
    for (int q = 0; q < 4; ++q)
        A_cat[(size_t)b * 2 * IN_ + tid + q * 256] = acc[q];
}

__global__ __launch_bounds__(256) void add_bias_k(
    const float* __restrict__ a, const float* __restrict__ b, float* __restrict__ o, int n)
{
    const int i = blockIdx.x * 256 + threadIdx.x;
    if (i < n) o[i] = a[i] + b[i];
}

__global__ __launch_bounds__(256) void finalize_k(
    const float* __restrict__ out_full, const float* __restrict__ c_buf,
    float* __restrict__ hT, float* __restrict__ cT)
{
    const int idx = blockIdx.x * 256 + threadIdx.x;  // < B*H
    const int b = idx >> 10;
    const int j = idx & 1023;
    hT[idx] = out_full[(size_t)b * T_ * H_ + (size_t)(T_ - 1) * H_ + j];
    cT[idx] = c_buf[idx];
}

extern "C" void kernel_launch(void* const* d_in, const int* in_sizes, int n_in,
                              void* d_out, int out_size, void* d_ws, size_t ws_size,
                              hipStream_t stream) {
    const float* target = (const float*)d_in[0];   // (B,T,IN)
    const float* h0     = (const float*)d_in[1];   // (B,H)
    const float* c0     = (const float*)d_in[2];   // (B,H)
    const float* ctx    = (const float*)d_in[3];   // (B,S,2IN)
    const float* mask   = (const float*)d_in[4];   // (B,S)
    const float* W_ih   = (const float*)d_in[5];   // (4H,IN)
    const float* b_ih   = (const float*)d_in[6];   // (4H)
    const float* W_hh   = (const float*)d_in[7];   // (4H,H)
    const float* b_hh   = (const float*)d_in[8];   // (4H)
    const float* W_in   = (const float*)d_in[9];   // (IN,H)
    const float* W_ctx  = (const float*)d_in[10];  // (IN,2IN)
    const float* W_out  = (const float*)d_in[11];  // (H,2IN)

    float* out = (float*)d_out;                    // (B,T,H)
    float* hT  = out + (size_t)B_ * T_ * H_;
    float* cT  = hT + (size_t)B_ * H_;

    float* ws        = (float*)d_ws;
    float* dense_ctx = ws;                                   // B*S*IN       = 8388608
    float* xW        = dense_ctx + (size_t)B_ * S_ * IN_;    // B*T*4H       = 8388608
    float* gates     = xW + (size_t)B_ * T_ * 4 * H_;        // B*4H         = 262144
    float* c_buf     = gates + (size_t)B_ * 4 * H_;          // B*H          = 65536
    float* hy        = c_buf + (size_t)B_ * H_;              // B*H          = 65536
    float* A_cat     = hy + (size_t)B_ * H_;                 // B*2IN        = 131072
    float* bias_sum  = A_cat + (size_t)B_ * 2 * IN_;         // 4H           = 4096

    // bias_sum = b_ih + b_hh
    add_bias_k<<<16, 256, 0, stream>>>(b_ih, b_hh, bias_sum, 4 * H_);
    // c_buf = c0
    hipMemcpyAsync(c_buf, c0, sizeof(float) * B_ * H_, hipMemcpyDeviceToDevice, stream);

    // dense_ctx[b*S+s, c] = sum_d ctx[b*S+s, d] * W_ctx[c, d]   M=8192 N=1024 K=2048
    {
        dim3 g(IN_ / 64, (B_ * S_) / 64);
        gemm_abt<<<g, 256, 0, stream>>>(ctx, 2 * IN_, W_ctx, 2 * IN_, dense_ctx, IN_,
                                        2 * IN_, nullptr, nullptr, 0, 0);
    }
    // xW[b*T+t, n] = sum_k target * W_ih + bias_sum             M=2048 N=4096 K=1024
    {
        dim3 g(4 * H_ / 64, (B_ * T_) / 64);
        gemm_abt<<<g, 256, 0, stream>>>(target, IN_, W_ih, IN_, xW, 4 * H_,
                                        IN_, bias_sum, nullptr, 0, 0);
    }

    for (int t = 0; t < T_; ++t) {
        const float* hx = (t == 0) ? h0 : (out + (size_t)(t - 1) * H_);
        const long lda_h = (t == 0) ? H_ : (long)T_ * H_;

        // gates = hx @ W_hh^T + xW[:,t,:]                       M=64 N=4096 K=1024
        {
            dim3 g(4 * H_ / 64, 1);
            gemm_abt<<<g, 256, 0, stream>>>(hx, lda_h, W_hh, H_, gates, 4 * H_,
                                            H_, nullptr, xW + (size_t)t * 4 * H_,
                                            (long)T_ * 4 * H_, 0);
        }
        lstm_cell<<<(B_ * H_) / 256, 256, 0, stream>>>(gates, c_buf, hy);

        // inp = hy @ W_in^T -> A_cat[:,1024:2048]               M=64 N=1024 K=1024
        {
            dim3 g(IN_ / 64, 1);
            gemm_abt<<<g, 256, 0, stream>>>(hy, H_, W_in, H_, A_cat + IN_, 2 * IN_,
                                            H_, nullptr, nullptr, 0, 0);
        }
        attn_kernel<<<B_, 256, 0, stream>>>(dense_ctx, A_cat, mask);

        // h_tilde = tanh(A_cat @ W_out^T) -> out[:,t,:]         M=64 N=1024 K=2048
        {
            dim3 g(H_ / 64, 1);
            gemm_abt<<<g, 256, 0, stream>>>(A_cat, 2 * IN_, W_out, 2 * IN_,
                                            out + (size_t)t * H_, (long)T_ * H_,
                                            2 * IN_, nullptr, nullptr, 0, 1);
        }
    }

    finalize_k<<<(B_ * H_) / 256, 256, 0, stream>>>(out, c_buf, hT, cT);
}

// Round 2
// 2053.091 us; speedup vs baseline: 6.4877x; 6.4877x over previous
//
#include <hip/hip_runtime.h>
#include <cstddef>

#define B_ 64
#define T_ 32
#define S_ 128
#define IN_ 1024
#define H_ 1024

typedef __bf16 bf16x8 __attribute__((ext_vector_type(8)));
typedef float f32x4 __attribute__((ext_vector_type(4)));

__device__ __forceinline__ float sigmoidf_(float x) { return 1.0f / (1.0f + expf(-x)); }

__device__ __forceinline__ ushort f2bf(float x) {
    unsigned u = __builtin_bit_cast(unsigned, x);
    unsigned r = (u + 0x7fffu + ((u >> 16) & 1u)) >> 16;
    return (ushort)r;
}
__device__ __forceinline__ float bf2f(ushort h) {
    unsigned u = ((unsigned)h) << 16;
    return __builtin_bit_cast(float, u);
}

// Convert 8 fp32 -> 8 bf16 hi + 8 bf16 lo, store 16B each to LDS.
__device__ __forceinline__ void cvt_store(ushort* __restrict__ dhi, ushort* __restrict__ dlo,
                                          float4 a, float4 b) {
    float xs[8] = {a.x, a.y, a.z, a.w, b.x, b.y, b.z, b.w};
    unsigned hp[4], lp[4];
#pragma unroll
    for (int i = 0; i < 4; ++i) {
        ushort h0 = f2bf(xs[2 * i]);
        ushort h1 = f2bf(xs[2 * i + 1]);
        ushort l0 = f2bf(xs[2 * i] - bf2f(h0));
        ushort l1 = f2bf(xs[2 * i + 1] - bf2f(h1));
        hp[i] = (unsigned)h0 | ((unsigned)h1 << 16);
        lp[i] = (unsigned)l0 | ((unsigned)l1 << 16);
    }
    *reinterpret_cast<uint4*>(dhi) = make_uint4(hp[0], hp[1], hp[2], hp[3]);
    *reinterpret_cast<uint4*>(dlo) = make_uint4(lp[0], lp[1], lp[2], lp[3]);
}

// C[M,N] = A[M,K] @ B[N,K]^T in split-bf16 (hi/lo), fp32 inputs converted at stage time.
// Tile 64x64, 256 threads = 4 waves (2x2), each wave 32x32 via 2x2 MFMA 16x16x32 frags.
// grid.z = split-K slices; partial=1 -> write slice partials to Cout[z][M][N].
__global__ __launch_bounds__(256) void gemm_sb(
    const float* __restrict__ A, long lda,
    const float* __restrict__ Bw, long ldb,
    int Ktile, int M, int N,
    float* __restrict__ Cout, long ldc,
    const float* __restrict__ bias, int partial)
{
    __shared__ alignas(16) ushort Ah[64][40];
    __shared__ alignas(16) ushort Al[64][40];
    __shared__ alignas(16) ushort Bh[64][40];
    __shared__ alignas(16) ushort Bl[64][40];

    const int tid = threadIdx.x;
    const int m0 = blockIdx.y << 6, n0 = blockIdx.x << 6;
    const int z = blockIdx.z;
    const long kbase = (long)z * Ktile;
    const int lrow = tid >> 2, lkc = tid & 3;

    const float* Ap = A + (size_t)(m0 + lrow) * lda + kbase + lkc * 8;
    const float* Bp = Bw + (size_t)(n0 + lrow) * ldb + kbase + lkc * 8;

    const int lane = tid & 63, wv = tid >> 6;
    const int wm = wv >> 1, wn = wv & 1;
    const int fr = lane & 15, fc = lane >> 4;

    const f32x4 zero4 = {0.f, 0.f, 0.f, 0.f};
    f32x4 acc00 = zero4, acc01 = zero4, acc10 = zero4, acc11 = zero4;

    float4 ra0 = *(const float4*)(Ap);
    float4 ra1 = *(const float4*)(Ap + 4);
    float4 rb0 = *(const float4*)(Bp);
    float4 rb1 = *(const float4*)(Bp + 4);

    for (int k0 = 0; k0 < Ktile; k0 += 32) {
        cvt_store(&Ah[lrow][lkc * 8], &Al[lrow][lkc * 8], ra0, ra1);
        cvt_store(&Bh[lrow][lkc * 8], &Bl[lrow][lkc * 8], rb0, rb1);
        __syncthreads();
        if (k0 + 32 < Ktile) {  // prefetch next tile while MFMAs run
            ra0 = *(const float4*)(Ap + k0 + 32);
            ra1 = *(const float4*)(Ap + k0 + 36);
            rb0 = *(const float4*)(Bp + k0 + 32);
            rb1 = *(const float4*)(Bp + k0 + 36);
        }
        bf16x8 ah0 = *(const bf16x8*)&Ah[wm * 32 + fr][fc * 8];
        bf16x8 ah1 = *(const bf16x8*)&Ah[wm * 32 + 16 + fr][fc * 8];
        bf16x8 al0 = *(const bf16x8*)&Al[wm * 32 + fr][fc * 8];
        bf16x8 al1 = *(const bf16x8*)&Al[wm * 32 + 16 + fr][fc * 8];
        bf16x8 bh0 = *(const bf16x8*)&Bh[wn * 32 + fr][fc * 8];
        bf16x8 bh1 = *(const bf16x8*)&Bh[wn * 32 + 16 + fr][fc * 8];
        bf16x8 bl0 = *(const bf16x8*)&Bl[wn * 32 + fr][fc * 8];
        bf16x8 bl1 = *(const bf16x8*)&Bl[wn * 32 + 16 + fr][fc * 8];

        acc00 = __builtin_amdgcn_mfma_f32_16x16x32_bf16(ah0, bh0, acc00, 0, 0, 0);
        acc00 = __builtin_amdgcn_mfma_f32_16x16x32_bf16(ah0, bl0, acc00, 0, 0, 0);
        acc00 = __builtin_amdgcn_mfma_f32_16x16x32_bf16(al0, bh0, acc00, 0, 0, 0);

        acc01 = __builtin_amdgcn_mfma_f32_16x16x32_bf16(ah0, bh1, acc01, 0, 0, 0);
        acc01 = __builtin_amdgcn_mfma_f32_16x16x32_bf16(ah0, bl1, acc01, 0, 0, 0);
        acc01 = __builtin_amdgcn_mfma_f32_16x16x32_bf16(al0, bh1, acc01, 0, 0, 0);

        acc10 = __builtin_amdgcn_mfma_f32_16x16x32_bf16(ah1, bh0, acc10, 0, 0, 0);
        acc10 = __builtin_amdgcn_mfma_f32_16x16x32_bf16(ah1, bl0, acc10, 0, 0, 0);
        acc10 = __builtin_amdgcn_mfma_f32_16x16x32_bf16(al1, bh0, acc10, 0, 0, 0);

        acc11 = __builtin_amdgcn_mfma_f32_16x16x32_bf16(ah1, bh1, acc11, 0, 0, 0);
        acc11 = __builtin_amdgcn_mfma_f32_16x16x32_bf16(ah1, bl1, acc11, 0, 0, 0);
        acc11 = __builtin_amdgcn_mfma_f32_16x16x32_bf16(al1, bh1, acc11, 0, 0, 0);
        __syncthreads();
    }

    const int mb = m0 + wm * 32 + fc * 4;
    const int nb = n0 + wn * 32 + fr;
    if (partial) {
        float* cp = Cout + (size_t)z * M * N;
#pragma unroll
        for (int i = 0; i < 4; ++i) {
            cp[(size_t)(mb + i) * N + nb]           = acc00[i];
            cp[(size_t)(mb + i) * N + nb + 16]      = acc01[i];
            cp[(size_t)(mb + 16 + i) * N + nb]      = acc10[i];
            cp[(size_t)(mb + 16 + i) * N + nb + 16] = acc11[i];
        }
    } else {
        float b0 = 0.f, b1 = 0.f;
        if (bias) { b0 = bias[nb]; b1 = bias[nb + 16]; }
#pragma unroll
        for (int i = 0; i < 4; ++i) {
            Cout[(size_t)(mb + i) * ldc + nb]           = acc00[i] + b0;
            Cout[(size_t)(mb + i) * ldc + nb + 16]      = acc01[i] + b1;
            Cout[(size_t)(mb + 16 + i) * ldc + nb]      = acc10[i] + b0;
            Cout[(size_t)(mb + 16 + i) * ldc + nb + 16] = acc11[i] + b1;
        }
    }
}

// Sum 4 split-K partials of gates, add precomputed xW_t (already has biases), LSTM cell.
__global__ __launch_bounds__(256) void reduce_lstm(
    const float* __restrict__ part, const float* __restrict__ xWt, long ldxw,
    float* __restrict__ c_buf, float* __restrict__ hy)
{
    const int idx = blockIdx.x * 256 + threadIdx.x;  // < B*H
    const int b = idx >> 10, j = idx & 1023;
    const float* p = part + (size_t)b * 4096 + j;
    const size_t sl = (size_t)B_ * 4096;
    float gi = 0.f, gf = 0.f, gg = 0.f, go = 0.f;
#pragma unroll
    for (int z = 0; z < 4; ++z) {
        gi += p[z * sl];
        gf += p[z * sl + 1024];
        gg += p[z * sl + 2048];
        go += p[z * sl + 3072];
    }
    const float* xw = xWt + (size_t)b * ldxw;
    gi += xw[j]; gf += xw[j + 1024]; gg += xw[j + 2048]; go += xw[j + 3072];
    const float c = sigmoidf_(gf) * c_buf[idx] + sigmoidf_(gi) * tanhf(gg);
    c_buf[idx] = c;
    hy[idx] = sigmoidf_(go) * tanhf(c);
}

// Sum 8 split-K partials of inp -> A_cat[:,1024:2048]
__global__ __launch_bounds__(256) void reduce_in(
    const float* __restrict__ part, float* __restrict__ A_cat)
{
    const int idx = blockIdx.x * 256 + threadIdx.x;  // < B*IN
    const int b = idx >> 10, c = idx & 1023;
    float v = 0.f;
#pragma unroll
    for (int z = 0; z < 8; ++z) v += part[(size_t)z * B_ * IN_ + idx];
    A_cat[(size_t)b * 2 * IN_ + IN_ + c] = v;
}

// Sum 8 split-K partials, tanh -> out[:,t,:] and h_cur
__global__ __launch_bounds__(256) void reduce_out(
    const float* __restrict__ part, float* __restrict__ outp, float* __restrict__ h_cur)
{
    const int idx = blockIdx.x * 256 + threadIdx.x;  // < B*H
    const int b = idx >> 10, j = idx & 1023;
    float v = 0.f;
#pragma unroll
    for (int z = 0; z < 8; ++z) v += part[(size_t)z * B_ * H_ + idx];
    v = tanhf(v);
    outp[(size_t)b * T_ * H_ + j] = v;
    h_cur[idx] = v;
}

// One block per batch. scores = dense_ctx[b] @ inp - neg; softmax; wctx = a @ dense_ctx[b].
__global__ __launch_bounds__(512) void attn_kernel(
    const float* __restrict__ dc_all, float* __restrict__ A_cat,
    const float* __restrict__ mask)
{
    const int b = blockIdx.x;
    const int tid = threadIdx.x;
    const int lane = tid & 63;
    const int wid = tid >> 6;

    __shared__ float sc[S_];
    __shared__ alignas(16) float sinp[IN_];

    const float* dc = dc_all + (size_t)b * S_ * IN_;
    float* ac = A_cat + (size_t)b * 2 * IN_;

    sinp[tid] = ac[IN_ + tid];
    sinp[tid + 512] = ac[IN_ + 512 + tid];
    __syncthreads();

    const float4* sinp4 = (const float4*)sinp;
    for (int s = wid; s < S_; s += 8) {
        const float4* row = (const float4*)(dc + (size_t)s * IN_);
        float sum = 0.f;
#pragma unroll
        for (int it = 0; it < 4; ++it) {
            float4 v = row[lane + it * 64];
            float4 w = sinp4[lane + it * 64];
            sum += v.x * w.x + v.y * w.y + v.z * w.z + v.w * w.w;
        }
#pragma unroll
        for (int off = 32; off > 0; off >>= 1) sum += __shfl_xor(sum, off);
        if (lane == 0)
            sc[s] = sum - (1.0f - mask[(size_t)b * S_ + s]) * 100000.0f;
    }
    __syncthreads();

    if (tid < 64) {
        float v0 = sc[tid], v1 = sc[tid + 64];
        float mx = fmaxf(v0, v1);
#pragma unroll
        for (int off = 32; off > 0; off >>= 1) mx = fmaxf(mx, __shfl_xor(mx, off));
        float e0 = expf(v0 - mx), e1 = expf(v1 - mx);
        float ssum = e0 + e1;
#pragma unroll
        for (int off = 32; off > 0; off >>= 1) ssum += __shfl_xor(ssum, off);
        const float inv = 1.0f / ssum;
        sc[tid] = e0 * inv;
        sc[tid + 64] = e1 * inv;
    }
    __syncthreads();

    float2 acc = {0.f, 0.f};
    const float2* dc2 = (const float2*)dc;
#pragma unroll 4
    for (int s = 0; s < S_; ++s) {
        const float a = sc[s];
        float2 v = dc2[(size_t)s * (IN_ / 2) + tid];
        acc.x += a * v.x;
        acc.y += a * v.y;
    }
    ac[2 * tid] = acc.x;
    ac[2 * tid + 1] = acc.y;
}

__global__ __launch_bounds__(256) void add_bias_k(
    const float* __restrict__ a, const float* __restrict__ b, float* __restrict__ o, int n)
{
    const int i = blockIdx.x * 256 + threadIdx.x;
    if (i < n) o[i] = a[i] + b[i];
}

extern "C" void kernel_launch(void* const* d_in, const int* in_sizes, int n_in,
                              void* d_out, int out_size, void* d_ws, size_t ws_size,
                              hipStream_t stream) {
    const float* target = (const float*)d_in[0];   // (B,T,IN)
    const float* h0     = (const float*)d_in[1];   // (B,H)
    const float* c0     = (const float*)d_in[2];   // (B,H)
    const float* ctx    = (const float*)d_in[3];   // (B,S,2IN)
    const float* mask   = (const float*)d_in[4];   // (B,S)
    const float* W_ih   = (const float*)d_in[5];   // (4H,IN)
    const float* b_ih   = (const float*)d_in[6];   // (4H)
    const float* W_hh   = (const float*)d_in[7];   // (4H,H)
    const float* b_hh   = (const float*)d_in[8];   // (4H)
    const float* W_in   = (const float*)d_in[9];   // (IN,H)
    const float* W_ctx  = (const float*)d_in[10];  // (IN,2IN)
    const float* W_out  = (const float*)d_in[11];  // (H,2IN)

    float* out = (float*)d_out;                    // (B,T,H)
    float* hT  = out + (size_t)B_ * T_ * H_;
    float* cT  = hT + (size_t)B_ * H_;

    float* ws        = (float*)d_ws;
    float* dense_ctx = ws;                                    // 8388608
    float* xW        = dense_ctx + (size_t)B_ * S_ * IN_;     // 8388608
    float* part_g    = xW + (size_t)B_ * T_ * 4 * H_;         // 4*64*4096 = 1048576
    float* part_i    = part_g + (size_t)4 * B_ * 4 * H_;      // 8*64*1024 = 524288
    float* part_o    = part_i + (size_t)8 * B_ * IN_;         // 524288
    float* c_buf     = part_o + (size_t)8 * B_ * H_;          // 65536
    float* hy        = c_buf + (size_t)B_ * H_;               // 65536
    float* A_cat     = hy + (size_t)B_ * H_;                  // 131072
    float* h_cur     = A_cat + (size_t)B_ * 2 * IN_;          // 65536
    float* bias_sum  = h_cur + (size_t)B_ * H_;               // 4096

    add_bias_k<<<16, 256, 0, stream>>>(b_ih, b_hh, bias_sum, 4 * H_);
    hipMemcpyAsync(c_buf, c0, sizeof(float) * B_ * H_, hipMemcpyDeviceToDevice, stream);

    // dense_ctx = ctx @ W_ctx^T     M=8192 N=1024 K=2048
    gemm_sb<<<dim3(IN_ / 64, (B_ * S_) / 64, 1), 256, 0, stream>>>(
        ctx, 2 * IN_, W_ctx, 2 * IN_, 2 * IN_, B_ * S_, IN_, dense_ctx, IN_, nullptr, 0);

    // xW = target @ W_ih^T + bias   M=2048 N=4096 K=1024
    gemm_sb<<<dim3(4 * H_ / 64, (B_ * T_) / 64, 1), 256, 0, stream>>>(
        target, IN_, W_ih, IN_, IN_, B_ * T_, 4 * H_, xW, 4 * H_, bias_sum, 0);

    for (int t = 0; t < T_; ++t) {
        const float* hx = (t == 0) ? h0 : h_cur;

        // gates partials: hx @ W_hh^T    M=64 N=4096 K=1024, KS=4
        gemm_sb<<<dim3(4 * H_ / 64, 1, 4), 256, 0, stream>>>(
            hx, H_, W_hh, H_, H_ / 4, B_, 4 * H_, part_g, 0, nullptr, 1);
        reduce_lstm<<<256, 256, 0, stream>>>(part_g, xW + (size_t)t * 4 * H_,
                                             (long)T_ * 4 * H_, c_buf, hy);

        // inp partials: hy @ W_in^T      M=64 N=1024 K=1024, KS=8
        gemm_sb<<<dim3(IN_ / 64, 1, 8), 256, 0, stream>>>(
            hy, H_, W_in, H_, H_ / 8, B_, IN_, part_i, 0, nullptr, 1);
        reduce_in<<<256, 256, 0, stream>>>(part_i, A_cat);

        attn_kernel<<<B_, 512, 0, stream>>>(dense_ctx, A_cat, mask);

        // out partials: A_cat @ W_out^T  M=64 N=1024 K=2048, KS=8
        gemm_sb<<<dim3(H_ / 64, 1, 8), 256, 0, stream>>>(
            A_cat, 2 * IN_, W_out, 2 * IN_, 2 * IN_ / 8, B_, H_, part_o, 0, nullptr, 1);
        reduce_out<<<256, 256, 0, stream>>>(part_o, out + (size_t)t * H_, h_cur);
    }

    hipMemcpyAsync(hT, h_cur, sizeof(float) * B_ * H_, hipMemcpyDeviceToDevice, stream);
    hipMemcpyAsync(cT, c_buf, sizeof(float) * B_ * H_, hipMemcpyDeviceToDevice, stream);
}

// Round 3
// 1643.223 us; speedup vs baseline: 8.1059x; 1.2494x over previous
//
#include <hip/hip_runtime.h>
#include <cstddef>

#define B_ 64
#define T_ 32
#define S_ 128
#define IN_ 1024
#define H_ 1024

typedef __bf16 bf16x8 __attribute__((ext_vector_type(8)));
typedef float f32x4 __attribute__((ext_vector_type(4)));

__device__ __forceinline__ float sigmoidf_(float x) { return 1.0f / (1.0f + expf(-x)); }

__device__ __forceinline__ ushort f2bf(float x) {
    unsigned u = __builtin_bit_cast(unsigned, x);
    unsigned r = (u + 0x7fffu + ((u >> 16) & 1u)) >> 16;
    return (ushort)r;
}
__device__ __forceinline__ float bf2f(ushort h) {
    unsigned u = ((unsigned)h) << 16;
    return __builtin_bit_cast(float, u);
}

// async global->LDS, 16B per lane; lds dest must be wave-uniform (HW adds lane*16).
__device__ __forceinline__ void gll16(const ushort* g, ushort* l) {
    __builtin_amdgcn_global_load_lds(
        (const __attribute__((address_space(1))) void*)g,
        (__attribute__((address_space(3))) void*)l,
        16, 0, 0);
}

// C[M,N] = A[M,K] @ B[N,K]^T with bf16 hi/lo planes (split-bf16).
// Block: 256 threads = 4 waves (2x2). Wave tile = 16*FM x 16*FN. Block = 32FM x 32FN.
// BK=64. LDS staged in MFMA fragment order: 16x32 subtiles of 1KB, linear lane*16.
template<int FM, int FN, bool ALO, bool BLO>
__global__ __launch_bounds__(256) void gemm_bf(
    const ushort* __restrict__ Ah_g, const ushort* __restrict__ Al_g, long lda,
    const ushort* __restrict__ Bh_g, const ushort* __restrict__ Bl_g, long ldb,
    int Ktile, int M, int N,
    float* __restrict__ Cf, ushort* __restrict__ Cb,
    const float* __restrict__ bias, int partial)
{
    constexpr int NSA = 4 * FM;              // subtiles per A plane
    constexpr int NSB = 4 * FN;
    constexpr int OAL = NSA;                 // A-lo plane base (if ALO)
    constexpr int OBH = NSA * (ALO ? 2 : 1); // B-hi plane base
    constexpr int OBL = OBH + NSB;           // B-lo plane base (if BLO)
    constexpr int NST = OBH + NSB * (BLO ? 2 : 1);
    __shared__ ushort lds[NST * 512];

    const int tid = threadIdx.x;
    const int lane = tid & 63, wv = tid >> 6;
    const int wm = wv >> 1, wn = wv & 1;
    const int m0 = blockIdx.y * (FM * 32), n0 = blockIdx.x * (FN * 32);
    const long kbase = (long)blockIdx.z * Ktile;
    const int lr = lane & 15, lc = lane >> 4;

    f32x4 acc[FM][FN];
#pragma unroll
    for (int i = 0; i < FM; ++i)
#pragma unroll
        for (int j = 0; j < FN; ++j) acc[i][j] = (f32x4){0.f, 0.f, 0.f, 0.f};

    for (int k0 = 0; k0 < Ktile; k0 += 64) {
        const long kp = kbase + k0;
#pragma unroll
        for (int q = 0; q < NST / 4; ++q) {
            const int si = wv * (NST / 4) + q;
            const ushort* P; long ld; int row0; int st;
            if (si < OBH) {
                if (ALO && si >= NSA) { P = Al_g; st = si - NSA; }
                else                  { P = Ah_g; st = si; }
                ld = lda; row0 = m0;
            } else {
                const int sj = si - OBH;
                if (BLO && sj >= NSB) { P = Bl_g; st = sj - NSB; }
                else                  { P = Bh_g; st = sj; }
                ld = ldb; row0 = n0;
            }
            const int row = ((st >> 1) << 4) + lr;
            const int kc = ((st & 1) << 5) + (lc << 3);
            gll16(P + (size_t)(row0 + row) * ld + kp + kc, &lds[si * 512]);
        }
        __syncthreads();
#pragma unroll
        for (int ks = 0; ks < 2; ++ks) {
            bf16x8 ah[FM], al[FM], bh[FN], bl[FN];
#pragma unroll
            for (int i = 0; i < FM; ++i) {
                const int st = (wm * FM + i) * 2 + ks;
                ah[i] = *(const bf16x8*)&lds[st * 512 + lane * 8];
                if (ALO) al[i] = *(const bf16x8*)&lds[(OAL + st) * 512 + lane * 8];
            }
#pragma unroll
            for (int j = 0; j < FN; ++j) {
                const int st = (wn * FN + j) * 2 + ks;
                bh[j] = *(const bf16x8*)&lds[(OBH + st) * 512 + lane * 8];
                if (BLO) bl[j] = *(const bf16x8*)&lds[(OBL + st) * 512 + lane * 8];
            }
#pragma unroll
            for (int i = 0; i < FM; ++i)
#pragma unroll
                for (int j = 0; j < FN; ++j) {
                    acc[i][j] = __builtin_amdgcn_mfma_f32_16x16x32_bf16(ah[i], bh[j], acc[i][j], 0, 0, 0);
                    if (BLO) acc[i][j] = __builtin_amdgcn_mfma_f32_16x16x32_bf16(ah[i], bl[j], acc[i][j], 0, 0, 0);
                    if (ALO) acc[i][j] = __builtin_amdgcn_mfma_f32_16x16x32_bf16(al[i], bh[j], acc[i][j], 0, 0, 0);
                }
        }
        __syncthreads();
    }

    const int fr = lane & 15, fc = lane >> 4;
    if (partial) {
        float* cp = Cf + (size_t)blockIdx.z * M * N;
#pragma unroll
        for (int i = 0; i < FM; ++i)
#pragma unroll
            for (int j = 0; j < FN; ++j) {
                const int mb = m0 + wm * FM * 16 + i * 16 + fc * 4;
                const int nb = n0 + wn * FN * 16 + j * 16 + fr;
#pragma unroll
                for (int r = 0; r < 4; ++r)
                    cp[(size_t)(mb + r) * N + nb] = acc[i][j][r];
            }
    } else if (Cb) {
#pragma unroll
        for (int i = 0; i < FM; ++i)
#pragma unroll
            for (int j = 0; j < FN; ++j) {
                const int mb = m0 + wm * FM * 16 + i * 16 + fc * 4;
                const int nb = n0 + wn * FN * 16 + j * 16 + fr;
#pragma unroll
                for (int r = 0; r < 4; ++r)
                    Cb[(size_t)(mb + r) * N + nb] = f2bf(acc[i][j][r]);
            }
    } else {
#pragma unroll
        for (int i = 0; i < FM; ++i)
#pragma unroll
            for (int j = 0; j < FN; ++j) {
                const int mb = m0 + wm * FM * 16 + i * 16 + fc * 4;
                const int nb = n0 + wn * FN * 16 + j * 16 + fr;
                const float bv = bias ? bias[nb] : 0.f;
#pragma unroll
                for (int r = 0; r < 4; ++r)
                    Cf[(size_t)(mb + r) * N + nb] = acc[i][j][r] + bv;
            }
    }
}

__global__ __launch_bounds__(256) void cvt2_k(
    const float* __restrict__ in, ushort* __restrict__ hi, ushort* __restrict__ lo, int n4)
{
    const int i = blockIdx.x * 256 + threadIdx.x;
    if (i >= n4) return;
    const float4 v = ((const float4*)in)[i];
    ushort4 h, l;
    h.x = f2bf(v.x); l.x = f2bf(v.x - bf2f(h.x));
    h.y = f2bf(v.y); l.y = f2bf(v.y - bf2f(h.y));
    h.z = f2bf(v.z); l.z = f2bf(v.z - bf2f(h.z));
    h.w = f2bf(v.w); l.w = f2bf(v.w - bf2f(h.w));
    ((ushort4*)hi)[i] = h;
    ((ushort4*)lo)[i] = l;
}

__global__ __launch_bounds__(256) void cvt1_k(
    const float* __restrict__ in, ushort* __restrict__ hi, int n4)
{
    const int i = blockIdx.x * 256 + threadIdx.x;
    if (i >= n4) return;
    const float4 v = ((const float4*)in)[i];
    ushort4 h;
    h.x = f2bf(v.x); h.y = f2bf(v.y); h.z = f2bf(v.z); h.w = f2bf(v.w);
    ((ushort4*)hi)[i] = h;
}

// Sum 4 split-K partials of gates + xW_t (has biases), LSTM cell, emit hy bf16 planes.
__global__ __launch_bounds__(256) void reduce_lstm(
    const float* __restrict__ part, const float* __restrict__ xWt,
    float* __restrict__ c_buf, ushort* __restrict__ hy_h, ushort* __restrict__ hy_l)
{
    const int idx = blockIdx.x * 256 + threadIdx.x;  // < B*H
    const int b = idx >> 10, j = idx & 1023;
    const float* p = part + (size_t)b * 4096 + j;
    const size_t sl = (size_t)B_ * 4096;
    float gi = 0.f, gf = 0.f, gg = 0.f, go = 0.f;
#pragma unroll
    for (int z = 0; z < 4; ++z) {
        gi += p[z * sl];
        gf += p[z * sl + 1024];
        gg += p[z * sl + 2048];
        go += p[z * sl + 3072];
    }
    const float* xw = xWt + (size_t)b * T_ * 4096;
    gi += xw[j]; gf += xw[j + 1024]; gg += xw[j + 2048]; go += xw[j + 3072];
    const float c = sigmoidf_(gf) * c_buf[idx] + sigmoidf_(gi) * tanhf(gg);
    c_buf[idx] = c;
    const float h = sigmoidf_(go) * tanhf(c);
    const ushort hh = f2bf(h);
    hy_h[idx] = hh;
    hy_l[idx] = f2bf(h - bf2f(hh));
}

// Sum 16 split-K partials, tanh -> out[:,t,:] (fp32) and h planes (bf16).
__global__ __launch_bounds__(256) void reduce_out(
    const float* __restrict__ part, float* __restrict__ outp,
    ushort* __restrict__ h_h, ushort* __restrict__ h_l)
{
    const int idx = blockIdx.x * 256 + threadIdx.x;  // < B*H
    const int b = idx >> 10, j = idx & 1023;
    float v = 0.f;
#pragma unroll
    for (int z = 0; z < 16; ++z) v += part[(size_t)z * B_ * H_ + idx];
    v = tanhf(v);
    outp[(size_t)b * T_ * H_ + j] = v;
    const ushort hh = f2bf(v);
    h_h[idx] = hh;
    h_l[idx] = f2bf(v - bf2f(hh));
}

// One block per batch. Fused: reduce 16 inp partials -> sinp + A_cat[:,1024:2048] planes;
// scores from bf16 dense_ctx; softmax; wctx -> A_cat[:,0:1024] planes.
__global__ __launch_bounds__(512) void attn_kernel(
    const ushort* __restrict__ dc_all, const float* __restrict__ part_i,
    ushort* __restrict__ Ah, ushort* __restrict__ Al, const float* __restrict__ mask)
{
    const int b = blockIdx.x;
    const int tid = threadIdx.x;
    const int lane = tid & 63;
    const int wid = tid >> 6;

    __shared__ alignas(16) float sinp[IN_];
    __shared__ float sc[S_];

#pragma unroll
    for (int r = 0; r < 2; ++r) {
        const int j = tid + r * 512;
        float v = 0.f;
#pragma unroll
        for (int z = 0; z < 16; ++z) v += part_i[(size_t)z * B_ * IN_ + (size_t)b * IN_ + j];
        sinp[j] = v;
        const ushort h = f2bf(v);
        Ah[(size_t)b * 2048 + 1024 + j] = h;
        Al[(size_t)b * 2048 + 1024 + j] = f2bf(v - bf2f(h));
    }
    __syncthreads();

    const ushort* dc = dc_all + (size_t)b * S_ * IN_;
    for (int s = wid; s < S_; s += 8) {
        const ushort* row = dc + (size_t)s * IN_;
        float sum = 0.f;
#pragma unroll
        for (int it = 0; it < 2; ++it) {
            const int e = it * 512 + lane * 8;
            const uint4 v = *(const uint4*)(row + e);
            const float4 w0 = *(const float4*)&sinp[e];
            const float4 w1 = *(const float4*)&sinp[e + 4];
            sum += bf2f(v.x & 0xffff) * w0.x + bf2f(v.x >> 16) * w0.y
                 + bf2f(v.y & 0xffff) * w0.z + bf2f(v.y >> 16) * w0.w
                 + bf2f(v.z & 0xffff) * w1.x + bf2f(v.z >> 16) * w1.y
                 + bf2f(v.w & 0xffff) * w1.z + bf2f(v.w >> 16) * w1.w;
        }
#pragma unroll
        for (int off = 32; off > 0; off >>= 1) sum += __shfl_xor(sum, off);
        if (lane == 0)
            sc[s] = sum - (1.0f - mask[(size_t)b * S_ + s]) * 100000.0f;
    }
    __syncthreads();

    if (tid < 64) {
        float v0 = sc[tid], v1 = sc[tid + 64];
        float mx = fmaxf(v0, v1);
#pragma unroll
        for (int off = 32; off > 0; off >>= 1) mx = fmaxf(mx, __shfl_xor(mx, off));
        float e0 = expf(v0 - mx), e1 = expf(v1 - mx);
        float ssum = e0 + e1;
#pragma unroll
        for (int off = 32; off > 0; off >>= 1) ssum += __shfl_xor(ssum, off);
        const float inv = 1.0f / ssum;
        sc[tid] = e0 * inv;
        sc[tid + 64] = e1 * inv;
    }
    __syncthreads();

    float ax = 0.f, ay = 0.f;
#pragma unroll 4
    for (int s = 0; s < S_; ++s) {
        const float a = sc[s];
        const unsigned v = *(const unsigned*)(dc + (size_t)s * IN_ + 2 * tid);
        ax += a * bf2f(v & 0xffff);
        ay += a * bf2f(v >> 16);
    }
    const ushort hx = f2bf(ax), hy2 = f2bf(ay);
    Ah[(size_t)b * 2048 + 2 * tid] = hx;
    Ah[(size_t)b * 2048 + 2 * tid + 1] = hy2;
    Al[(size_t)b * 2048 + 2 * tid] = f2bf(ax - bf2f(hx));
    Al[(size_t)b * 2048 + 2 * tid + 1] = f2bf(ay - bf2f(hy2));
}

__global__ __launch_bounds__(256) void add_bias_k(
    const float* __restrict__ a, const float* __restrict__ b, float* __restrict__ o, int n)
{
    const int i = blockIdx.x * 256 + threadIdx.x;
    if (i < n) o[i] = a[i] + b[i];
}

__global__ __launch_bounds__(256) void finalize_k(
    const float* __restrict__ out_full, const float* __restrict__ c_buf,
    float* __restrict__ hT, float* __restrict__ cT)
{
    const int idx = blockIdx.x * 256 + threadIdx.x;  // < B*H
    const int b = idx >> 10, j = idx & 1023;
    hT[idx] = out_full[(size_t)b * T_ * H_ + (size_t)(T_ - 1) * H_ + j];
    cT[idx] = c_buf[idx];
}

extern "C" void kernel_launch(void* const* d_in, const int* in_sizes, int n_in,
                              void* d_out, int out_size, void* d_ws, size_t ws_size,
                              hipStream_t stream) {
    const float* target = (const float*)d_in[0];   // (B,T,IN)
    const float* h0     = (const float*)d_in[1];   // (B,H)
    const float* c0     = (const float*)d_in[2];   // (B,H)
    const float* ctx    = (const float*)d_in[3];   // (B,S,2IN)
    const float* mask   = (const float*)d_in[4];   // (B,S)
    const float* W_ih   = (const float*)d_in[5];   // (4H,IN)
    const float* b_ih   = (const float*)d_in[6];   // (4H)
    const float* W_hh   = (const float*)d_in[7];   // (4H,H)
    const float* b_hh   = (const float*)d_in[8];   // (4H)
    const float* W_in   = (const float*)d_in[9];   // (IN,H)
    const float* W_ctx  = (const float*)d_in[10];  // (IN,2IN)
    const float* W_out  = (const float*)d_in[11];  // (H,2IN)

    float* out = (float*)d_out;                    // (B,T,H)
    float* hT  = out + (size_t)B_ * T_ * H_;
    float* cT  = hT + (size_t)B_ * H_;

    // ---- workspace layout (persistent then transient union) ----
    ushort* dc_b   = (ushort*)d_ws;                  // dense_ctx bf16: 8,388,608
    float*  xW     = (float*)(dc_b + 8388608);       // 8,388,608 f32
    ushort* Whh_h  = (ushort*)(xW + 8388608);        // 4,194,304
    ushort* Whh_l  = Whh_h + 4194304;
    ushort* Win_h  = Whh_l + 4194304;                // 1,048,576
    ushort* Win_l  = Win_h + 1048576;
    ushort* Wout_h = Win_l + 1048576;                // 2,097,152
    ushort* Wout_l = Wout_h + 2097152;
    float*  bias_sum = (float*)(Wout_l + 2097152);   // 4096
    char*   trans  = (char*)(bias_sum + 4096);
    // phase A (pre-loop):
    ushort* ctx_h  = (ushort*)trans;                 // 16,777,216
    ushort* tgt_h  = ctx_h + 16777216;               // 2,097,152
    ushort* tgt_l  = tgt_h + 2097152;
    ushort* Wih_h  = tgt_l + 2097152;                // 4,194,304
    ushort* Wih_l  = Wih_h + 4194304;
    ushort* Wctx_h = Wih_l + 4194304;                // 2,097,152
    ushort* Wctx_l = Wctx_h + 2097152;
    // phase B (loop; aliases phase A):
    float* part_g = (float*)trans;                   // 4*64*4096
    float* part_i = part_g + 1048576;                // 16*64*1024
    float* part_o = part_i + 1048576;                // 16*64*1024
    float* c_buf  = part_o + 1048576;                // 65536
    ushort* hy_h  = (ushort*)(c_buf + 65536);        // 65536 each below
    ushort* hy_l  = hy_h + 65536;
    ushort* hc_h  = hy_l + 65536;
    ushort* hc_l  = hc_h + 65536;
    ushort* Ac_h  = hc_l + 65536;                    // 131072
    ushort* Ac_l  = Ac_h + 131072;

    // ---- pre-conversions ----
    add_bias_k<<<16, 256, 0, stream>>>(b_ih, b_hh, bias_sum, 4 * H_);
    cvt1_k<<<16384, 256, 0, stream>>>(ctx, ctx_h, 4194304);
    cvt2_k<<<2048, 256, 0, stream>>>(target, tgt_h, tgt_l, 524288);
    cvt2_k<<<4096, 256, 0, stream>>>(W_ih, Wih_h, Wih_l, 1048576);
    cvt2_k<<<4096, 256, 0, stream>>>(W_hh, Whh_h, Whh_l, 1048576);
    cvt2_k<<<1024, 256, 0, stream>>>(W_in, Win_h, Win_l, 262144);
    cvt2_k<<<2048, 256, 0, stream>>>(W_ctx, Wctx_h, Wctx_l, 524288);
    cvt2_k<<<2048, 256, 0, stream>>>(W_out, Wout_h, Wout_l, 524288);

    // dense_ctx (bf16 out) = ctx @ W_ctx^T    M=8192 N=1024 K=2048  (A 2-term)
    gemm_bf<4, 4, false, true><<<dim3(8, 64, 1), 256, 0, stream>>>(
        ctx_h, nullptr, 2 * IN_, Wctx_h, Wctx_l, 2 * IN_,
        2 * IN_, B_ * S_, IN_, nullptr, dc_b, nullptr, 0);

    // xW = target @ W_ih^T + bias             M=2048 N=4096 K=1024
    gemm_bf<4, 4, true, true><<<dim3(32, 16, 1), 256, 0, stream>>>(
        tgt_h, tgt_l, IN_, Wih_h, Wih_l, IN_,
        IN_, B_ * T_, 4 * H_, xW, nullptr, bias_sum, 0);

    // loop-state init (after big GEMMs: aliased region)
    cvt2_k<<<64, 256, 0, stream>>>(h0, hc_h, hc_l, 16384);
    hipMemcpyAsync(c_buf, c0, sizeof(float) * B_ * H_, hipMemcpyDeviceToDevice, stream);

    for (int t = 0; t < T_; ++t) {
        // gates partials: h @ W_hh^T          M=64 N=4096 K=1024, KS=4
        gemm_bf<2, 2, true, true><<<dim3(64, 1, 4), 256, 0, stream>>>(
            hc_h, hc_l, H_, Whh_h, Whh_l, H_,
            256, B_, 4 * H_, part_g, nullptr, nullptr, 1);
        reduce_lstm<<<256, 256, 0, stream>>>(part_g, xW + (size_t)t * 4 * H_,
                                             c_buf, hy_h, hy_l);

        // inp partials: hy @ W_in^T           M=64 N=1024 K=1024, KS=16
        gemm_bf<2, 2, true, true><<<dim3(16, 1, 16), 256, 0, stream>>>(
            hy_h, hy_l, H_, Win_h, Win_l, H_,
            64, B_, IN_, part_i, nullptr, nullptr, 1);

        attn_kernel<<<B_, 512, 0, stream>>>(dc_b, part_i, Ac_h, Ac_l, mask);

        // out partials: A_cat @ W_out^T       M=64 N=1024 K=2048, KS=16
        gemm_bf<2, 2, true, true><<<dim3(16, 1, 16), 256, 0, stream>>>(
            Ac_h, Ac_l, 2 * IN_, Wout_h, Wout_l, 2 * IN_,
            128, B_, H_, part_o, nullptr, nullptr, 1);
        reduce_out<<<256, 256, 0, stream>>>(part_o, out + (size_t)t * H_, hc_h, hc_l);
    }

    finalize_k<<<256, 256, 0, stream>>>(out, c_buf, hT, cT);
}